// Round 13
// baseline (1519.463 us; speedup 1.0000x reference)
//
#include <hip/hip_runtime.h>
#include <hip/hip_fp16.h>

#define FEAT 64
#define HID 10
#define RS 16    // fp32 row stride (floats) -> 64B rows
#define BRS 4    // packed-fp12 B row stride (dwords) -> 16B rows
#define BSH 6    // bucket shift: 64 nodes per bucket
#define CHK 32   // block-rows per chunk in column-prefix passes
#define NBLK 1024 // persistent grid: 4 blocks/CU x 256 CU (co-resident: VGPR<=128 via launch_bounds, LDS 4x34.5KB<160KB)
#define TPB 256

typedef __attribute__((ext_vector_type(2))) float f32x2;

#if defined(__has_builtin)
#if __has_builtin(__builtin_elementwise_fma)
#define HAVE_EW_FMA 1
#endif
#endif

__device__ __forceinline__ f32x2 pk_fma(f32x2 a, f32x2 b, f32x2 c) {
#ifdef HAVE_EW_FMA
    return __builtin_elementwise_fma(a, b, c);
#else
    f32x2 r; r.x = fmaf(a.x, b.x, c.x); r.y = fmaf(a.y, b.y, c.y); return r;
#endif
}
__device__ __forceinline__ f32x2 pk_max0(f32x2 a) {
    f32x2 r; r.x = fmaxf(a.x, 0.f); r.y = fmaxf(a.y, 0.f); return r;
}

// ---- fp12 (s1e5m6 = top 12 bits of fp16, RTN) codec ----
__device__ __forceinline__ unsigned int f2fp12(float v) {
    unsigned short h = __half_as_ushort(__float2half(v));
    return (((unsigned int)h) + 8u) >> 4;
}
__device__ __forceinline__ float fp12f(unsigned int f) {
    return __half2float(__ushort_as_half((unsigned short)(f << 4)));
}
__device__ __forceinline__ uint4 pack10(const float* b) {
    unsigned int f[10];
#pragma unroll
    for (int i = 0; i < 10; i++) f[i] = f2fp12(b[i]);
    uint4 d;
    d.x = f[0] | (f[1] << 12) | (f[2] << 24);
    d.y = (f[2] >> 8) | (f[3] << 4) | (f[4] << 16) | (f[5] << 28);
    d.z = (f[5] >> 4) | (f[6] << 8) | (f[7] << 20);
    d.w = f[8] | (f[9] << 12);
    return d;
}

// ---- grid barrier: monotonic counter; RELAXED spin (no invalidates), single acquire on exit ----
__device__ __forceinline__ void gbar(int* cnt, int target) {
    __syncthreads();
    if (threadIdx.x == 0) {
        // RELEASE add: orders/flushes our prior global writes to the coherent point.
        __hip_atomic_fetch_add(cnt, 1, __ATOMIC_RELEASE, __HIP_MEMORY_SCOPE_AGENT);
        // RELAXED polling: coherent-point load, NO cache invalidate per iteration.
        while (__hip_atomic_load(cnt, __ATOMIC_RELAXED, __HIP_MEMORY_SCOPE_AGENT) < target)
            __builtin_amdgcn_s_sleep(16);
        // One acquire to invalidate stale cached data before consuming peers' writes.
        (void)__hip_atomic_load(cnt, __ATOMIC_ACQUIRE, __HIP_MEMORY_SCOPE_AGENT);
    }
    __syncthreads();
}

// ---- fused gather layer (grid-stride over 4*n_nodes quad-slots) ----
template<bool LAST>
__device__ __forceinline__ void gather_phase(
    float* smem_f, const float* __restrict__ A, const unsigned int* __restrict__ Bt,
    const float* __restrict__ W1, const float* __restrict__ W2n,
    const int* __restrict__ startv, const int* __restrict__ nbr,
    float* __restrict__ An, unsigned int* __restrict__ Bn, float* __restrict__ Hout,
    int n_nodes, int g)
{
    if (!LAST) {
        for (int i = threadIdx.x; i < 200; i += TPB) smem_f[i] = W2n[i];
    }
    __syncthreads();

    f32x2 w1p[10][5];
#pragma unroll
    for (int j = 0; j < 10; j++)
#pragma unroll
        for (int h2 = 0; h2 < 5; h2++)
            w1p[j][h2] = (f32x2){ W1[j * 10 + 2 * h2], W1[j * 10 + 2 * h2 + 1] };

    const int total = 4 * n_nodes;
    for (int slot = g; slot < total; slot += NBLK * TPB) {
        int n = slot >> 2;
        int q = slot & 3;

        const float4* ar = reinterpret_cast<const float4*>(A + (size_t)n * RS);
        float4 a0 = ar[0], a1 = ar[1], a2 = ar[2];
        f32x2 av2[5] = { {a0.x,a0.y}, {a0.z,a0.w}, {a1.x,a1.y}, {a1.z,a1.w}, {a2.x,a2.y} };

        f32x2 acc2[5];
#pragma unroll
        for (int h2 = 0; h2 < 5; h2++) acc2[h2] = (f32x2){0.f, 0.f};

        int beg = startv[n];
        int end = startv[n + 1];
        for (int i = beg + q; i < end; i += 4) {
            int s = nbr[i];
            uint4 d = *reinterpret_cast<const uint4*>(Bt + (size_t)s * BRS);
            unsigned int f0 = d.x & 0xFFFu;
            unsigned int f1 = (d.x >> 12) & 0xFFFu;
            unsigned int f2 = (d.x >> 24) | ((d.y & 0xFu) << 8);
            unsigned int f3 = (d.y >> 4) & 0xFFFu;
            unsigned int f4 = (d.y >> 16) & 0xFFFu;
            unsigned int f5 = ((d.y >> 28) & 0xFu) | ((d.z & 0xFFu) << 4);
            unsigned int f6 = (d.z >> 8) & 0xFFFu;
            unsigned int f7 = d.z >> 20;
            unsigned int f8 = d.w & 0xFFFu;
            unsigned int f9 = (d.w >> 12) & 0xFFFu;

            f32x2 pre[5];
            pre[0] = av2[0] + (f32x2){ fp12f(f0), fp12f(f1) };
            pre[1] = av2[1] + (f32x2){ fp12f(f2), fp12f(f3) };
            pre[2] = av2[2] + (f32x2){ fp12f(f4), fp12f(f5) };
            pre[3] = av2[3] + (f32x2){ fp12f(f6), fp12f(f7) };
            pre[4] = av2[4] + (f32x2){ fp12f(f8), fp12f(f9) };
#pragma unroll
            for (int k = 0; k < 5; k++) pre[k] = pk_max0(pre[k]);

            f32x2 z[5];
#pragma unroll
            for (int h2 = 0; h2 < 5; h2++) z[h2] = (f32x2){0.f, 0.f};
#pragma unroll
            for (int j2 = 0; j2 < 5; j2++) {
                f32x2 pa = (f32x2){ pre[j2].x, pre[j2].x };
                f32x2 pb = (f32x2){ pre[j2].y, pre[j2].y };
#pragma unroll
                for (int h2 = 0; h2 < 5; h2++) {
                    z[h2] = pk_fma(pa, w1p[2 * j2][h2], z[h2]);
                    z[h2] = pk_fma(pb, w1p[2 * j2 + 1][h2], z[h2]);
                }
            }
#pragma unroll
            for (int h2 = 0; h2 < 5; h2++) acc2[h2] += pk_max0(z[h2]);
        }

#pragma unroll
        for (int h2 = 0; h2 < 5; h2++) {
            acc2[h2].x += __shfl_xor(acc2[h2].x, 1);
            acc2[h2].y += __shfl_xor(acc2[h2].y, 1);
        }
#pragma unroll
        for (int h2 = 0; h2 < 5; h2++) {
            acc2[h2].x += __shfl_xor(acc2[h2].x, 2);
            acc2[h2].y += __shfl_xor(acc2[h2].y, 2);
        }

        float hv[10];
#pragma unroll
        for (int h2 = 0; h2 < 5; h2++) {
            hv[2 * h2]     = acc2[h2].x * 0.1f;
            hv[2 * h2 + 1] = acc2[h2].y * 0.1f;
        }

        if (LAST) {
            float* Hr = Hout + (size_t)n * RS;
            if (q == 0)      *reinterpret_cast<float4*>(Hr)     = make_float4(hv[0], hv[1], hv[2], hv[3]);
            else if (q == 1) *reinterpret_cast<float4*>(Hr + 4) = make_float4(hv[4], hv[5], hv[6], hv[7]);
            else if (q == 2) *reinterpret_cast<float2*>(Hr + 8) = make_float2(hv[8], hv[9]);
        } else {
            if (q == 0) {
                float a[8];
#pragma unroll
                for (int h = 0; h < 8; h++) {
                    float zz = 0.f;
#pragma unroll
                    for (int k = 0; k < 10; k++) zz = fmaf(hv[k], smem_f[k * 10 + h], zz);
                    a[h] = zz;
                }
                float4* Ar = reinterpret_cast<float4*>(An + (size_t)n * RS);
                Ar[0] = make_float4(a[0], a[1], a[2], a[3]);
                Ar[1] = make_float4(a[4], a[5], a[6], a[7]);
            } else if (q == 1) {
                float a8 = 0.f, a9 = 0.f;
#pragma unroll
                for (int k = 0; k < 10; k++) {
                    a8 = fmaf(hv[k], smem_f[k * 10 + 8], a8);
                    a9 = fmaf(hv[k], smem_f[k * 10 + 9], a9);
                }
                *reinterpret_cast<float2*>(An + (size_t)n * RS + 8) = make_float2(a8, a9);
            } else if (q == 2) {
                float bb[10];
#pragma unroll
                for (int h = 0; h < 10; h++) {
                    float zz = 0.f;
#pragma unroll
                    for (int k = 0; k < 10; k++) zz = fmaf(hv[k], smem_f[100 + k * 10 + h], zz);
                    bb[h] = zz;
                }
                *reinterpret_cast<uint4*>(Bn + (size_t)n * BRS) = pack10(bb);
            }
        }
    }
}

// =================== THE mega-kernel: entire model, 1 launch ===================
__global__ __launch_bounds__(TPB, 4) void mega_k(
    const float* __restrict__ X, const float* __restrict__ W2_0,
    const float* __restrict__ W1_0, const float* __restrict__ W2_1,
    const float* __restrict__ W1_1, const float* __restrict__ W2_2,
    const float* __restrict__ W1_2, const float* __restrict__ Wf1,
    const float* __restrict__ Wf2,
    const int* __restrict__ src, const int* __restrict__ dst,
    float* __restrict__ out,
    float* A0, float* A1, unsigned int* B0, unsigned int* B1, float* H,
    int* nbr, int* packedv, int* blockhist, int* chunksum, int* btot,
    int* bbase, int* bstart, int* startv, int* cnt,
    int n_edges, int n_nodes, int nbk)
{
    __shared__ int smem_i[8832];            // 34.5 KB, overlaid per phase
    float* smem_f = (float*)smem_i;
    const int b = blockIdx.x;
    const int t = threadIdx.x;
    const int g = b * TPB + t;
    const int EPBm = (n_edges + NBLK - 1) / NBLK;
    const int nchk = (NBLK + CHK - 1) / CHK;   // 32

    // ---- P1: per-block bucket histogram (LDS) ----
    for (int i = t; i < nbk; i += TPB) smem_i[i] = 0;
    __syncthreads();
    {
        int e0 = b * EPBm, e1 = min(e0 + EPBm, n_edges);
        for (int e = e0 + t; e < e1; e += TPB) atomicAdd(&smem_i[dst[e] >> BSH], 1);
    }
    __syncthreads();
    for (int i = t; i < nbk; i += TPB) blockhist[(size_t)b * nbk + i] = smem_i[i];
    gbar(cnt, NBLK * 1);

    // ---- P2: chunk column sums (transposed chunksum[bb*nchk+c]) ----
    if (g < nbk * nchk) {
        int bb = g % nbk, c = g / nbk;
        int k0 = c * CHK, k1 = min(k0 + CHK, NBLK);
        int s = 0;
        for (int k = k0; k < k1; k++) s += blockhist[(size_t)k * nbk + bb];
        chunksum[(size_t)bb * nchk + c] = s;
    }
    gbar(cnt, NBLK * 2);

    // ---- P3: per-bucket scan over chunks ----
    if (g < nbk) {
        int run = 0;
        int* row = chunksum + (size_t)g * nchk;
        for (int c = 0; c < nchk; c++) { int v = row[c]; row[c] = run; run += v; }
        btot[g] = run;
    }
    gbar(cnt, NBLK * 3);

    // ---- P4: bucket-base exclusive scan (block 0) ----
    if (b == 0) {
        int v[8];
        int s = 0;
#pragma unroll
        for (int j = 0; j < 8; j++) {
            int idx = t * 8 + j;
            v[j] = (idx < nbk) ? btot[idx] : 0;
            s += v[j];
        }
        smem_i[t] = s;
        __syncthreads();
        for (int off = 1; off < 256; off <<= 1) {
            int x = (t >= off) ? smem_i[t - off] : 0;
            __syncthreads();
            smem_i[t] += x;
            __syncthreads();
        }
        int run = smem_i[t] - s;
#pragma unroll
        for (int j = 0; j < 8; j++) {
            int idx = t * 8 + j;
            if (idx < nbk) { bbase[idx] = run; bstart[idx] = run; }
            run += v[j];
        }
        if (t == 255) { bstart[nbk] = n_edges; startv[n_nodes] = n_edges; }
    }
    gbar(cnt, NBLK * 4);

    // ---- P5: per-(chunk,bucket) running offsets ----
    if (g < nbk * nchk) {
        int bb = g % nbk, c = g / nbk;
        int k0 = c * CHK, k1 = min(k0 + CHK, NBLK);
        int run = bbase[bb] + chunksum[(size_t)bb * nchk + c];
        for (int k = k0; k < k1; k++) {
            size_t idx = (size_t)k * nbk + bb;
            int v = blockhist[idx];
            blockhist[idx] = run;
            run += v;
        }
    }
    gbar(cnt, NBLK * 5);

    // ---- P6: bucket-grouped scatter (LDS cursors) ----
    for (int i = t; i < nbk; i += TPB) smem_i[i] = blockhist[(size_t)b * nbk + i];
    __syncthreads();
    {
        int e0 = b * EPBm, e1 = min(e0 + EPBm, n_edges);
        for (int e = e0 + t; e < e1; e += TPB) {
            int d = dst[e];
            int pos = atomicAdd(&smem_i[d >> BSH], 1);
            packedv[pos] = ((d & 63) << 17) | src[e];
        }
    }
    gbar(cnt, NBLK * 6);

    // ---- P7: per-bucket exact CSR ----
    for (int bkt = b; bkt < nbk; bkt += NBLK) {
        __syncthreads();
        int base = bstart[bkt];
        int end  = bstart[bkt + 1];
        int* hist = smem_i;
        int* excl = smem_i + 64;
        int* cur  = smem_i + 128;
        if (t < 64) hist[t] = 0;
        __syncthreads();
        for (int i = base + t; i < end; i += TPB) atomicAdd(&hist[packedv[i] >> 17], 1);
        __syncthreads();
        if (t == 0) { int r = 0; for (int k = 0; k < 64; k++) { excl[k] = r; r += hist[k]; } }
        __syncthreads();
        if (t < 64) {
            cur[t] = excl[t];
            int node = (bkt << 6) + t;
            if (node < n_nodes) startv[node] = base + excl[t];
        }
        __syncthreads();
        for (int i = base + t; i < end; i += TPB) {
            int p = packedv[i];
            int pos = base + atomicAdd(&cur[p >> 17], 1);
            nbr[pos] = p & 0x1FFFF;
        }
    }
    gbar(cnt, NBLK * 7);

    // ---- P8: layer-0 precompute A0 = X@W2t, B0 = pack(X@W2b) ----
    for (int i = t; i < 1280; i += TPB) smem_f[i] = W2_0[i];
    __syncthreads();
    for (int n = g; n < n_nodes; n += NBLK * TPB) {
        const float4* xr = reinterpret_cast<const float4*>(X + (size_t)n * FEAT);
        float a[10], bb[10];
#pragma unroll
        for (int h = 0; h < 10; h++) { a[h] = 0.f; bb[h] = 0.f; }
#pragma unroll
        for (int blk = 0; blk < 16; blk++) {
            float4 u = xr[blk];
            float xv[4] = { u.x, u.y, u.z, u.w };
#pragma unroll
            for (int j = 0; j < 4; j++) {
                int k = blk * 4 + j;
#pragma unroll
                for (int h = 0; h < 10; h++) {
                    a[h]  = fmaf(xv[j], smem_f[k * 10 + h], a[h]);
                    bb[h] = fmaf(xv[j], smem_f[(64 + k) * 10 + h], bb[h]);
                }
            }
        }
        float4* Ar = reinterpret_cast<float4*>(A0 + (size_t)n * RS);
        Ar[0] = make_float4(a[0], a[1], a[2], a[3]);
        Ar[1] = make_float4(a[4], a[5], a[6], a[7]);
        Ar[2] = make_float4(a[8], a[9], 0.f, 0.f);
        *reinterpret_cast<uint4*>(B0 + (size_t)n * BRS) = pack10(bb);
    }
    gbar(cnt, NBLK * 8);

    // ---- P9-P11: three gather layers (fused next-layer pre) ----
    gather_phase<false>(smem_f, A0, B0, W1_0, W2_1, startv, nbr, A1, B1, nullptr, n_nodes, g);
    gbar(cnt, NBLK * 9);
    gather_phase<false>(smem_f, A1, B1, W1_1, W2_2, startv, nbr, A0, B0, nullptr, n_nodes, g);
    gbar(cnt, NBLK * 10);
    gather_phase<true>(smem_f, A0, B0, W1_2, nullptr, startv, nbr, nullptr, nullptr, H, n_nodes, g);
    gbar(cnt, NBLK * 11);

    // ---- P12: final node MLP (64-node tiles) ----
    {
        float* wf1  = smem_f;
        float* wf2s = smem_f + 640;
        float* tT   = smem_f + 640 + 4096;
        for (int i = t; i < 640; i += TPB) wf1[i] = Wf1[i];
        for (int i = t; i < 4096; i += TPB) wf2s[i] = Wf2[i];

        for (int tile = b; tile * 64 < n_nodes; tile += NBLK) {
            __syncthreads();
            int node0 = tile * 64;
            {
                int r = t & 63;
                int gg = t >> 6;
                int node = node0 + r;
                float hv[10];
                if (node < n_nodes) {
                    const float4* hr = reinterpret_cast<const float4*>(H + (size_t)node * RS);
                    float4 h0 = hr[0], h1 = hr[1];
                    float2 h2 = *reinterpret_cast<const float2*>(H + (size_t)node * RS + 8);
                    hv[0]=h0.x; hv[1]=h0.y; hv[2]=h0.z; hv[3]=h0.w;
                    hv[4]=h1.x; hv[5]=h1.y; hv[6]=h1.z; hv[7]=h1.w;
                    hv[8]=h2.x; hv[9]=h2.y;
                } else {
#pragma unroll
                    for (int k = 0; k < 10; k++) hv[k] = 0.f;
                }
#pragma unroll
                for (int j = 0; j < 16; j++) {
                    int c = gg * 16 + j;
                    float v = 0.f;
#pragma unroll
                    for (int k = 0; k < 10; k++) v = fmaf(hv[k], wf1[k * 64 + c], v);
                    tT[c * 64 + r] = fmaxf(v, 0.f);
                }
            }
            __syncthreads();

            int r0 = (t >> 4) * 4;
            int c0 = (t & 15) * 4;
            float acc[4][4];
#pragma unroll
            for (int i = 0; i < 4; i++)
#pragma unroll
                for (int j = 0; j < 4; j++) acc[i][j] = 0.f;

            for (int k = 0; k < 64; k++) {
                float4 a = *reinterpret_cast<const float4*>(&tT[k * 64 + r0]);
                float4 bb = *reinterpret_cast<const float4*>(&wf2s[k * 64 + c0]);
                float av[4] = { a.x, a.y, a.z, a.w };
                float bv[4] = { bb.x, bb.y, bb.z, bb.w };
#pragma unroll
                for (int i = 0; i < 4; i++)
#pragma unroll
                    for (int j = 0; j < 4; j++)
                        acc[i][j] = fmaf(av[i], bv[j], acc[i][j]);
            }

#pragma unroll
            for (int i = 0; i < 4; i++) {
                int node = node0 + r0 + i;
                if (node < n_nodes) {
                    float4 o = make_float4(fmaxf(acc[i][0], 0.f), fmaxf(acc[i][1], 0.f),
                                           fmaxf(acc[i][2], 0.f), fmaxf(acc[i][3], 0.f));
                    *reinterpret_cast<float4*>(&out[(size_t)node * FEAT + c0]) = o;
                }
            }
        }
    }
}

extern "C" void kernel_launch(void* const* d_in, const int* in_sizes, int n_in,
                              void* d_out, int out_size, void* d_ws, size_t ws_size,
                              hipStream_t stream) {
    const float* X    = (const float*)d_in[0];
    const float* W2_0 = (const float*)d_in[1];
    const float* W1_0 = (const float*)d_in[2];
    const float* W2_1 = (const float*)d_in[3];
    const float* W1_1 = (const float*)d_in[4];
    const float* W2_2 = (const float*)d_in[5];
    const float* W1_2 = (const float*)d_in[6];
    const float* Wf1  = (const float*)d_in[7];
    const float* Wf2  = (const float*)d_in[8];
    const int* src = (const int*)d_in[9];
    const int* dst = (const int*)d_in[10];
    float* out = (float*)d_out;

    const int n_edges = in_sizes[9];
    const int n_nodes = in_sizes[0] / FEAT;

    const int nbk  = (n_nodes + 63) >> 6;      // coarse buckets (~1563, <=2048 for P4)
    const int nchk = (NBLK + CHK - 1) / CHK;   // 32

    const size_t h_elems = (size_t)n_nodes * RS;
    const size_t b_elems = (size_t)n_nodes * BRS;
    // ws layout (4B elems)
    const size_t offH   = 0;
    const size_t offA0  = offH  + h_elems;
    const size_t offA1  = offA0 + h_elems;
    const size_t offB0  = offA1 + h_elems;
    const size_t offB1  = offB0 + b_elems;
    const size_t offNbr = offB1 + b_elems;
    const size_t offPk  = offNbr + (size_t)n_edges;
    const size_t offBh  = offPk + (size_t)n_edges;
    const size_t offCs  = offBh + (size_t)NBLK * nbk;
    const size_t offBt  = offCs + (size_t)nbk * nchk;
    const size_t offBb  = offBt + (size_t)nbk;
    const size_t offBs  = offBb + (size_t)nbk;
    const size_t offSt  = offBs + (size_t)nbk + 1;
    const size_t offCnt = offSt + (size_t)n_nodes + 1;

    float* H            = (float*)d_ws + offH;
    float* A0           = (float*)d_ws + offA0;
    float* A1           = (float*)d_ws + offA1;
    unsigned int* B0    = (unsigned int*)d_ws + offB0;
    unsigned int* B1    = (unsigned int*)d_ws + offB1;
    int* nbr            = (int*)d_ws + offNbr;
    int* packedv        = (int*)d_ws + offPk;
    int* blockhist      = (int*)d_ws + offBh;
    int* chunksum       = (int*)d_ws + offCs;
    int* btot           = (int*)d_ws + offBt;
    int* bbase          = (int*)d_ws + offBb;
    int* bstart         = (int*)d_ws + offBs;
    int* startv         = (int*)d_ws + offSt;
    int* cnt            = (int*)d_ws + offCnt;

    // barrier counter must start at 0 (ws is poisoned with 0xAA)
    hipMemsetAsync(cnt, 0, sizeof(int), stream);

    mega_k<<<NBLK, TPB, 0, stream>>>(
        X, W2_0, W1_0, W2_1, W1_1, W2_2, W1_2, Wf1, Wf2, src, dst, out,
        A0, A1, B0, B1, H, nbr, packedv, blockhist, chunksum, btot,
        bbase, bstart, startv, cnt, n_edges, n_nodes, nbk);
}

// Round 14
// 570.726 us; speedup vs baseline: 2.6623x; 2.6623x over previous
//
#include <hip/hip_runtime.h>
#include <hip/hip_fp16.h>

#define FEAT 64
#define HID 10
#define RS 16    // fp32 row stride (floats) -> 64B rows
#define BRS 4    // packed-fp12 B row stride (dwords) -> 16B rows
#define BSH 6    // bucket shift: 64 nodes per bucket

typedef __attribute__((ext_vector_type(2))) float f32x2;

#if defined(__has_builtin)
#if __has_builtin(__builtin_elementwise_fma)
#define HAVE_EW_FMA 1
#endif
#endif

__device__ __forceinline__ f32x2 pk_fma(f32x2 a, f32x2 b, f32x2 c) {
#ifdef HAVE_EW_FMA
    return __builtin_elementwise_fma(a, b, c);
#else
    f32x2 r; r.x = fmaf(a.x, b.x, c.x); r.y = fmaf(a.y, b.y, c.y); return r;
#endif
}
__device__ __forceinline__ f32x2 pk_max0(f32x2 a) {
    f32x2 r; r.x = fmaxf(a.x, 0.f); r.y = fmaxf(a.y, 0.f); return r;
}

// ---- fp12 (s1e5m6 = top 12 bits of fp16, RTN) codec ----
__device__ __forceinline__ unsigned int f2fp12(float v) {
    unsigned short h = __half_as_ushort(__float2half(v));
    return (((unsigned int)h) + 8u) >> 4;
}
__device__ __forceinline__ float fp12f(unsigned int f) {
    return __half2float(__ushort_as_half((unsigned short)(f << 4)));
}
__device__ __forceinline__ uint4 pack10(const float* b) {
    unsigned int f[10];
#pragma unroll
    for (int i = 0; i < 10; i++) f[i] = f2fp12(b[i]);
    uint4 d;
    d.x = f[0] | (f[1] << 12) | (f[2] << 24);
    d.y = (f[2] >> 8) | (f[3] << 4) | (f[4] << 16) | (f[5] << 28);
    d.z = (f[5] >> 4) | (f[6] << 8) | (f[7] << 20);
    d.w = f[8] | (f[9] << 12);
    return d;
}

// ---------- Layer-0 precompute: A=X@W2[0:64,:] (fp32), B=X@W2[64:128,:] (fp12 packed) ----------
__global__ __launch_bounds__(256) void pre_l0(
    const float* __restrict__ X,    // [NN,64]
    const float* __restrict__ W2,   // [128,10]
    float* __restrict__ A,          // [NN,RS] fp32
    unsigned int* __restrict__ Bt,  // [NN,BRS] packed fp12
    int n_nodes)
{
    __shared__ float w2[128 * 10];
    for (int i = threadIdx.x; i < 1280; i += 256) w2[i] = W2[i];
    __syncthreads();

    int n = blockIdx.x * 256 + threadIdx.x;
    if (n >= n_nodes) return;

    const float4* xr = reinterpret_cast<const float4*>(X + (size_t)n * FEAT);
    float a[10], b[10];
#pragma unroll
    for (int h = 0; h < 10; h++) { a[h] = 0.f; b[h] = 0.f; }

#pragma unroll
    for (int blk = 0; blk < 16; blk++) {
        float4 u = xr[blk];
        float xv[4] = { u.x, u.y, u.z, u.w };
#pragma unroll
        for (int j = 0; j < 4; j++) {
            int k = blk * 4 + j;
#pragma unroll
            for (int h = 0; h < 10; h++) {
                a[h] = fmaf(xv[j], w2[k * 10 + h], a[h]);
                b[h] = fmaf(xv[j], w2[(64 + k) * 10 + h], b[h]);
            }
        }
    }

    float4* Ar = reinterpret_cast<float4*>(A + (size_t)n * RS);
    Ar[0] = make_float4(a[0], a[1], a[2], a[3]);
    Ar[1] = make_float4(a[4], a[5], a[6], a[7]);
    Ar[2] = make_float4(a[8], a[9], 0.f, 0.f);
    *reinterpret_cast<uint4*>(Bt + (size_t)n * BRS) = pack10(b);
}

// ================= CSR build v2: global-atomic buckets (order within bucket irrelevant) ========

// Bucket histogram: 1.25M atomics onto nbk (~1563) counters (L2-resident hot lines).
__global__ __launch_bounds__(256) void ghist_k(
    const int* __restrict__ dst, int* __restrict__ bcnt, int n_edges)
{
    int e = blockIdx.x * 256 + threadIdx.x;
    if (e >= n_edges) return;
    atomicAdd(&bcnt[dst[e] >> BSH], 1);
}

// One-block exclusive scan of bucket counts -> bstart + cursor (nbk <= 2048).
__global__ __launch_bounds__(256) void scan_k(
    const int* __restrict__ bcnt, int* __restrict__ bstart,
    int* __restrict__ cursor, int* __restrict__ startv,
    int nbk, int n_nodes, int n_edges)
{
    __shared__ int ts[256];
    int t = threadIdx.x;
    int v[8];
    int s = 0;
#pragma unroll
    for (int j = 0; j < 8; j++) {
        int idx = t * 8 + j;
        v[j] = (idx < nbk) ? bcnt[idx] : 0;
        s += v[j];
    }
    ts[t] = s;
    __syncthreads();
    for (int off = 1; off < 256; off <<= 1) {
        int x = (t >= off) ? ts[t - off] : 0;
        __syncthreads();
        ts[t] += x;
        __syncthreads();
    }
    int run = ts[t] - s;
#pragma unroll
    for (int j = 0; j < 8; j++) {
        int idx = t * 8 + j;
        if (idx < nbk) { bstart[idx] = run; cursor[idx] = run; }
        run += v[j];
    }
    if (t == 255) { bstart[nbk] = n_edges; startv[n_nodes] = n_edges; }
}

// Scatter packed (dloc<<17 | src) into bucket-grouped regions via global cursors.
__global__ __launch_bounds__(256) void gscatter_k(
    const int* __restrict__ src, const int* __restrict__ dst,
    int* __restrict__ cursor, int* __restrict__ packedv, int n_edges)
{
    int e = blockIdx.x * 256 + threadIdx.x;
    if (e >= n_edges) return;
    int d = dst[e];
    int pos = atomicAdd(&cursor[d >> BSH], 1);
    packedv[pos] = ((d & 63) << 17) | src[e];
}

// One block per bucket -> exact per-node CSR (startv + nbr), cursors in LDS.
__global__ __launch_bounds__(256) void csr_k(
    const int* __restrict__ packedv, const int* __restrict__ bstart,
    int* __restrict__ nbr, int* __restrict__ startv, int n_nodes)
{
    __shared__ int hist[64];
    __shared__ int excl[64];
    __shared__ int cur[64];
    int b = blockIdx.x;
    int base = bstart[b];
    int end  = bstart[b + 1];
    if (threadIdx.x < 64) hist[threadIdx.x] = 0;
    __syncthreads();
    for (int i = base + threadIdx.x; i < end; i += 256)
        atomicAdd(&hist[packedv[i] >> 17], 1);
    __syncthreads();
    if (threadIdx.x == 0) {
        int r = 0;
        for (int k = 0; k < 64; k++) { excl[k] = r; r += hist[k]; }
    }
    __syncthreads();
    if (threadIdx.x < 64) {
        cur[threadIdx.x] = excl[threadIdx.x];
        int node = (b << 6) + threadIdx.x;
        if (node < n_nodes) startv[node] = base + excl[threadIdx.x];
    }
    __syncthreads();
    for (int i = base + threadIdx.x; i < end; i += 256) {
        int p = packedv[i];
        int pos = base + atomicAdd(&cur[p >> 17], 1);
        nbr[pos] = p & 0x1FFFF;
    }
}

// ---- shared gather core: returns hv[10] for (n,q); quad-reduced across the 4 lanes ----
__device__ __forceinline__ void gather_core(
    const float* __restrict__ A, const unsigned int* __restrict__ Bt,
    const f32x2 (&w1p)[10][5], const int* __restrict__ startv,
    const int* __restrict__ nbr, int n, int q, float (&hv)[10])
{
    const float4* ar = reinterpret_cast<const float4*>(A + (size_t)n * RS);
    float4 a0 = ar[0], a1 = ar[1], a2 = ar[2];
    f32x2 av2[5] = { {a0.x,a0.y}, {a0.z,a0.w}, {a1.x,a1.y}, {a1.z,a1.w}, {a2.x,a2.y} };

    f32x2 acc2[5];
#pragma unroll
    for (int h2 = 0; h2 < 5; h2++) acc2[h2] = (f32x2){0.f, 0.f};

    int beg = startv[n];
    int end = startv[n + 1];
    for (int i = beg + q; i < end; i += 4) {
        int s = nbr[i];
        uint4 d = *reinterpret_cast<const uint4*>(Bt + (size_t)s * BRS);
        unsigned int f0 = d.x & 0xFFFu;
        unsigned int f1 = (d.x >> 12) & 0xFFFu;
        unsigned int f2 = (d.x >> 24) | ((d.y & 0xFu) << 8);
        unsigned int f3 = (d.y >> 4) & 0xFFFu;
        unsigned int f4 = (d.y >> 16) & 0xFFFu;
        unsigned int f5 = ((d.y >> 28) & 0xFu) | ((d.z & 0xFFu) << 4);
        unsigned int f6 = (d.z >> 8) & 0xFFFu;
        unsigned int f7 = d.z >> 20;
        unsigned int f8 = d.w & 0xFFFu;
        unsigned int f9 = (d.w >> 12) & 0xFFFu;

        f32x2 pre[5];
        pre[0] = av2[0] + (f32x2){ fp12f(f0), fp12f(f1) };
        pre[1] = av2[1] + (f32x2){ fp12f(f2), fp12f(f3) };
        pre[2] = av2[2] + (f32x2){ fp12f(f4), fp12f(f5) };
        pre[3] = av2[3] + (f32x2){ fp12f(f6), fp12f(f7) };
        pre[4] = av2[4] + (f32x2){ fp12f(f8), fp12f(f9) };
#pragma unroll
        for (int k = 0; k < 5; k++) pre[k] = pk_max0(pre[k]);

        f32x2 z[5];
#pragma unroll
        for (int h2 = 0; h2 < 5; h2++) z[h2] = (f32x2){0.f, 0.f};
#pragma unroll
        for (int j2 = 0; j2 < 5; j2++) {
            f32x2 pa = (f32x2){ pre[j2].x, pre[j2].x };
            f32x2 pb = (f32x2){ pre[j2].y, pre[j2].y };
#pragma unroll
            for (int h2 = 0; h2 < 5; h2++) {
                z[h2] = pk_fma(pa, w1p[2 * j2][h2], z[h2]);
                z[h2] = pk_fma(pb, w1p[2 * j2 + 1][h2], z[h2]);
            }
        }
#pragma unroll
        for (int h2 = 0; h2 < 5; h2++) acc2[h2] += pk_max0(z[h2]);
    }

#pragma unroll
    for (int h2 = 0; h2 < 5; h2++) {
        acc2[h2].x += __shfl_xor(acc2[h2].x, 1);
        acc2[h2].y += __shfl_xor(acc2[h2].y, 1);
    }
#pragma unroll
    for (int h2 = 0; h2 < 5; h2++) {
        acc2[h2].x += __shfl_xor(acc2[h2].x, 2);
        acc2[h2].y += __shfl_xor(acc2[h2].y, 2);
    }
#pragma unroll
    for (int h2 = 0; h2 < 5; h2++) {
        hv[2 * h2]     = acc2[h2].x * 0.1f;
        hv[2 * h2 + 1] = acc2[h2].y * 0.1f;
    }
}

// ---------- Middle gather layers: h -> next A (fp32) + next B (fp12), fused pre ----------
__global__ __launch_bounds__(256) void gather_mid_k(
    const float* __restrict__ A, const unsigned int* __restrict__ Bt,
    const float* __restrict__ W1, const float* __restrict__ W2n,
    const int* __restrict__ startv, const int* __restrict__ nbr,
    float* __restrict__ An, unsigned int* __restrict__ Bn, int n_nodes)
{
    __shared__ float w2s[200];
    for (int i = threadIdx.x; i < 200; i += 256) w2s[i] = W2n[i];
    __syncthreads();

    f32x2 w1p[10][5];
#pragma unroll
    for (int j = 0; j < 10; j++)
#pragma unroll
        for (int h2 = 0; h2 < 5; h2++)
            w1p[j][h2] = (f32x2){ W1[j * 10 + 2 * h2], W1[j * 10 + 2 * h2 + 1] };

    int t = blockIdx.x * 256 + threadIdx.x;
    int n = t >> 2;
    int q = t & 3;
    if (n >= n_nodes) return;

    float hv[10];
    gather_core(A, Bt, w1p, startv, nbr, n, q, hv);

    if (q == 0) {
        float a[8];
#pragma unroll
        for (int h = 0; h < 8; h++) {
            float zz = 0.f;
#pragma unroll
            for (int k = 0; k < 10; k++) zz = fmaf(hv[k], w2s[k * 10 + h], zz);
            a[h] = zz;
        }
        float4* Ar = reinterpret_cast<float4*>(An + (size_t)n * RS);
        Ar[0] = make_float4(a[0], a[1], a[2], a[3]);
        Ar[1] = make_float4(a[4], a[5], a[6], a[7]);
    } else if (q == 1) {
        float a8 = 0.f, a9 = 0.f;
#pragma unroll
        for (int k = 0; k < 10; k++) {
            a8 = fmaf(hv[k], w2s[k * 10 + 8], a8);
            a9 = fmaf(hv[k], w2s[k * 10 + 9], a9);
        }
        *reinterpret_cast<float2*>(An + (size_t)n * RS + 8) = make_float2(a8, a9);
    } else if (q == 2) {
        float bb[10];
#pragma unroll
        for (int h = 0; h < 10; h++) {
            float zz = 0.f;
#pragma unroll
            for (int k = 0; k < 10; k++) zz = fmaf(hv[k], w2s[100 + k * 10 + h], zz);
            bb[h] = zz;
        }
        *reinterpret_cast<uint4*>(Bn + (size_t)n * BRS) = pack10(bb);
    }
}

// ---------- Last gather layer FUSED with final MLP: out = relu(relu(h@Wf1)@Wf2) ----------
// Block = 64 nodes (4 threads/node for gather, then 64x64 tile GEMM).
__global__ __launch_bounds__(256) void gather_fin_k(
    const float* __restrict__ A, const unsigned int* __restrict__ Bt,
    const float* __restrict__ W1,
    const int* __restrict__ startv, const int* __restrict__ nbr,
    const float* __restrict__ Wf1,  // [10,64]
    const float* __restrict__ Wf2,  // [64,64]
    float* __restrict__ out,        // [NN,64]
    int n_nodes)
{
    __shared__ float wf1[640];
    __shared__ float wf2s[4096];
    __shared__ float tT[4096];
    __shared__ float hvs[640];      // [64 nodes][10], stride 10 (2-way LDS alias: free)

    for (int i = threadIdx.x; i < 640; i += 256) wf1[i] = Wf1[i];
    for (int i = threadIdx.x; i < 4096; i += 256) wf2s[i] = Wf2[i];

    f32x2 w1p[10][5];
#pragma unroll
    for (int j = 0; j < 10; j++)
#pragma unroll
        for (int h2 = 0; h2 < 5; h2++)
            w1p[j][h2] = (f32x2){ W1[j * 10 + 2 * h2], W1[j * 10 + 2 * h2 + 1] };

    int t0 = blockIdx.x * 256 + threadIdx.x;
    int n = t0 >> 2;
    int q = t0 & 3;
    int r = threadIdx.x >> 2;       // node index within block (0..63)

    float hv[10];
#pragma unroll
    for (int k = 0; k < 10; k++) hv[k] = 0.f;
    if (n < n_nodes)
        gather_core(A, Bt, w1p, startv, nbr, n, q, hv);

    if (q == 0) {
#pragma unroll
        for (int k = 0; k < 5; k++) hvs[r * 10 + k] = hv[k];
    } else if (q == 1) {
#pragma unroll
        for (int k = 5; k < 10; k++) hvs[r * 10 + k] = hv[k];
    }
    __syncthreads();

    // Stage 1: tT[c][r] = relu(hv[r] @ Wf1[:,c])
    {
        int rr = threadIdx.x & 63;
        int gg = threadIdx.x >> 6;
        float h[10];
#pragma unroll
        for (int k = 0; k < 10; k++) h[k] = hvs[rr * 10 + k];
#pragma unroll
        for (int j = 0; j < 16; j++) {
            int c = gg * 16 + j;
            float v = 0.f;
#pragma unroll
            for (int k = 0; k < 10; k++) v = fmaf(h[k], wf1[k * 64 + c], v);
            tT[c * 64 + rr] = fmaxf(v, 0.f);
        }
    }
    __syncthreads();

    // Stage 2: 4x4 register tile over [64 nodes x 64 cols]
    int node0 = blockIdx.x * 64;
    int r0 = (threadIdx.x >> 4) * 4;
    int c0 = (threadIdx.x & 15) * 4;
    float acc[4][4];
#pragma unroll
    for (int i = 0; i < 4; i++)
#pragma unroll
        for (int j = 0; j < 4; j++) acc[i][j] = 0.f;

    for (int k = 0; k < 64; k++) {
        float4 a = *reinterpret_cast<const float4*>(&tT[k * 64 + r0]);
        float4 b = *reinterpret_cast<const float4*>(&wf2s[k * 64 + c0]);
        float av[4] = { a.x, a.y, a.z, a.w };
        float bv[4] = { b.x, b.y, b.z, b.w };
#pragma unroll
        for (int i = 0; i < 4; i++)
#pragma unroll
            for (int j = 0; j < 4; j++)
                acc[i][j] = fmaf(av[i], bv[j], acc[i][j]);
    }

#pragma unroll
    for (int i = 0; i < 4; i++) {
        int node = node0 + r0 + i;
        if (node < n_nodes) {
            float4 o = make_float4(fmaxf(acc[i][0], 0.f), fmaxf(acc[i][1], 0.f),
                                   fmaxf(acc[i][2], 0.f), fmaxf(acc[i][3], 0.f));
            *reinterpret_cast<float4*>(&out[(size_t)node * FEAT + c0]) = o;
        }
    }
}

extern "C" void kernel_launch(void* const* d_in, const int* in_sizes, int n_in,
                              void* d_out, int out_size, void* d_ws, size_t ws_size,
                              hipStream_t stream) {
    const float* X    = (const float*)d_in[0];
    const float* W2_0 = (const float*)d_in[1];
    const float* W1_0 = (const float*)d_in[2];
    const float* W2_1 = (const float*)d_in[3];
    const float* W1_1 = (const float*)d_in[4];
    const float* W2_2 = (const float*)d_in[5];
    const float* W1_2 = (const float*)d_in[6];
    const float* Wf1  = (const float*)d_in[7];
    const float* Wf2  = (const float*)d_in[8];
    const int* src = (const int*)d_in[9];
    const int* dst = (const int*)d_in[10];
    float* out = (float*)d_out;

    const int n_edges = in_sizes[9];
    const int n_nodes = in_sizes[0] / FEAT;

    const int nbk = (n_nodes + 63) >> 6;    // ~1563 buckets (<=2048 for scan_k)

    const size_t h_elems = (size_t)n_nodes * RS;
    const size_t b_elems = (size_t)n_nodes * BRS;
    // ws layout (4B elems): A0 | A1 | B0 | B1 | nbr | packed | bcnt | cursor | bstart | startv
    const size_t offA0  = 0;
    const size_t offA1  = offA0 + h_elems;
    const size_t offB0  = offA1 + h_elems;
    const size_t offB1  = offB0 + b_elems;
    const size_t offNbr = offB1 + b_elems;
    const size_t offPk  = offNbr + (size_t)n_edges;
    const size_t offBc  = offPk + (size_t)n_edges;
    const size_t offCu  = offBc + (size_t)nbk;
    const size_t offBs  = offCu + (size_t)nbk;
    const size_t offSt  = offBs + (size_t)nbk + 1;

    float* A0           = (float*)d_ws + offA0;
    float* A1           = (float*)d_ws + offA1;
    unsigned int* B0    = (unsigned int*)d_ws + offB0;
    unsigned int* B1    = (unsigned int*)d_ws + offB1;
    int* nbr            = (int*)d_ws + offNbr;
    int* packedv        = (int*)d_ws + offPk;
    int* bcnt           = (int*)d_ws + offBc;
    int* cursor         = (int*)d_ws + offCu;
    int* bstart         = (int*)d_ws + offBs;
    int* startv         = (int*)d_ws + offSt;

    const int nb = (n_nodes + 255) / 256;
    const int gb = (n_nodes * 4 + 255) / 256;   // == ceil(n_nodes/64)
    const int eb = (n_edges + 255) / 256;

    // ---- CSR build v2 (3 passes + per-bucket sort) ----
    hipMemsetAsync(bcnt, 0, (size_t)nbk * 4, stream);
    ghist_k<<<eb, 256, 0, stream>>>(dst, bcnt, n_edges);
    scan_k<<<1, 256, 0, stream>>>(bcnt, bstart, cursor, startv, nbk, n_nodes, n_edges);
    gscatter_k<<<eb, 256, 0, stream>>>(src, dst, cursor, packedv, n_edges);
    csr_k<<<nbk, 256, 0, stream>>>(packedv, bstart, nbr, startv, n_nodes);

    // ---- Layer 0 precompute + 2 mid gathers + fused last gather/final ----
    pre_l0<<<nb, 256, 0, stream>>>(X, W2_0, A0, B0, n_nodes);
    gather_mid_k<<<gb, 256, 0, stream>>>(A0, B0, W1_0, W2_1, startv, nbr, A1, B1, n_nodes);
    gather_mid_k<<<gb, 256, 0, stream>>>(A1, B1, W1_1, W2_2, startv, nbr, A0, B0, n_nodes);
    gather_fin_k<<<gb, 256, 0, stream>>>(A0, B0, W1_2, startv, nbr, Wf1, Wf2, out, n_nodes);
}

// Round 15
// 247.638 us; speedup vs baseline: 6.1358x; 2.3047x over previous
//
#include <hip/hip_runtime.h>
#include <hip/hip_fp16.h>

#define FEAT 64
#define HID 10
#define RS 16    // fp32 row stride (floats) -> 64B rows
#define BRS 4    // packed-fp12 B row stride (dwords) -> 16B rows
#define EPB 1024 // edges per block in binning passes -> ~1221 blocks
#define BSH 6    // bucket shift: 64 nodes per bucket
#define CHK 32   // block-rows per chunk in column-prefix passes

typedef __attribute__((ext_vector_type(2))) float f32x2;

#if defined(__has_builtin)
#if __has_builtin(__builtin_elementwise_fma)
#define HAVE_EW_FMA 1
#endif
#endif

__device__ __forceinline__ f32x2 pk_fma(f32x2 a, f32x2 b, f32x2 c) {
#ifdef HAVE_EW_FMA
    return __builtin_elementwise_fma(a, b, c);
#else
    f32x2 r; r.x = fmaf(a.x, b.x, c.x); r.y = fmaf(a.y, b.y, c.y); return r;
#endif
}
__device__ __forceinline__ f32x2 pk_max0(f32x2 a) {
    f32x2 r; r.x = fmaxf(a.x, 0.f); r.y = fmaxf(a.y, 0.f); return r;
}

// ---- fp12 (s1e5m6 = top 12 bits of fp16, RTN) codec ----
__device__ __forceinline__ unsigned int f2fp12(float v) {
    unsigned short h = __half_as_ushort(__float2half(v));
    return (((unsigned int)h) + 8u) >> 4;
}
__device__ __forceinline__ float fp12f(unsigned int f) {
    return __half2float(__ushort_as_half((unsigned short)(f << 4)));
}
__device__ __forceinline__ uint4 pack10(const float* b) {
    unsigned int f[10];
#pragma unroll
    for (int i = 0; i < 10; i++) f[i] = f2fp12(b[i]);
    uint4 d;
    d.x = f[0] | (f[1] << 12) | (f[2] << 24);
    d.y = (f[2] >> 8) | (f[3] << 4) | (f[4] << 16) | (f[5] << 28);
    d.z = (f[5] >> 4) | (f[6] << 8) | (f[7] << 20);
    d.w = f[8] | (f[9] << 12);
    return d;
}

// ---------- Layer-0 precompute: A=X@W2[0:64,:] (fp32), B=X@W2[64:128,:] (fp12 packed) ----------
__global__ __launch_bounds__(256) void pre_l0(
    const float* __restrict__ X,    // [NN,64]
    const float* __restrict__ W2,   // [128,10]
    float* __restrict__ A,          // [NN,RS] fp32
    unsigned int* __restrict__ Bt,  // [NN,BRS] packed fp12
    int n_nodes)
{
    __shared__ float w2[128 * 10];
    for (int i = threadIdx.x; i < 1280; i += 256) w2[i] = W2[i];
    __syncthreads();

    int n = blockIdx.x * 256 + threadIdx.x;
    if (n >= n_nodes) return;

    const float4* xr = reinterpret_cast<const float4*>(X + (size_t)n * FEAT);
    float a[10], b[10];
#pragma unroll
    for (int h = 0; h < 10; h++) { a[h] = 0.f; b[h] = 0.f; }

#pragma unroll
    for (int blk = 0; blk < 16; blk++) {
        float4 u = xr[blk];
        float xv[4] = { u.x, u.y, u.z, u.w };
#pragma unroll
        for (int j = 0; j < 4; j++) {
            int k = blk * 4 + j;
#pragma unroll
            for (int h = 0; h < 10; h++) {
                a[h] = fmaf(xv[j], w2[k * 10 + h], a[h]);
                b[h] = fmaf(xv[j], w2[(64 + k) * 10 + h], b[h]);
            }
        }
    }

    float4* Ar = reinterpret_cast<float4*>(A + (size_t)n * RS);
    Ar[0] = make_float4(a[0], a[1], a[2], a[3]);
    Ar[1] = make_float4(a[4], a[5], a[6], a[7]);
    Ar[2] = make_float4(a[8], a[9], 0.f, 0.f);
    *reinterpret_cast<uint4*>(Bt + (size_t)n * BRS) = pack10(b);
}

// ================= CSR build (R11-proven): two-level counting sort, LDS cursors only ==========

__global__ __launch_bounds__(256) void bin_hist_k(
    const int* __restrict__ dst, int* __restrict__ blockhist, int n_edges, int nbk)
{
    extern __shared__ int hist[];
    for (int i = threadIdx.x; i < nbk; i += 256) hist[i] = 0;
    __syncthreads();
    int base = blockIdx.x * EPB;
    for (int i = threadIdx.x; i < EPB; i += 256) {
        int e = base + i;
        if (e < n_edges) atomicAdd(&hist[dst[e] >> BSH], 1);
    }
    __syncthreads();
    int* row = blockhist + (size_t)blockIdx.x * nbk;
    for (int i = threadIdx.x; i < nbk; i += 256) row[i] = hist[i];
}

// chunksum is stored TRANSPOSED: chunksum[b * nchk + c]
__global__ __launch_bounds__(256) void colchunk_sum_k(
    const int* __restrict__ blockhist, int* __restrict__ chunksum,
    int nbk, int nblk, int nchk)
{
    int b = blockIdx.x * 256 + threadIdx.x;
    int c = blockIdx.y;
    if (b >= nbk) return;
    int k0 = c * CHK;
    int k1 = min(k0 + CHK, nblk);
    int s = 0;
    for (int k = k0; k < k1; k++) s += blockhist[(size_t)k * nbk + b];
    chunksum[(size_t)b * nchk + c] = s;
}

__global__ __launch_bounds__(256) void chunk_scan_k(
    int* __restrict__ chunksum, int* __restrict__ btot, int nbk, int nchk)
{
    int b = blockIdx.x * 256 + threadIdx.x;
    if (b >= nbk) return;
    int run = 0;
    int* row = chunksum + (size_t)b * nchk;   // contiguous walk
    for (int c = 0; c < nchk; c++) {
        int v = row[c];
        row[c] = run;
        run += v;
    }
    btot[b] = run;
}

__global__ __launch_bounds__(256) void scan_k(
    const int* __restrict__ btot, int* __restrict__ bbase,
    int* __restrict__ bucket_start, int* __restrict__ startv,
    int nbk, int n_nodes, int n_edges)
{
    __shared__ int ts[256];
    int t = threadIdx.x;
    int v[8];
    int s = 0;
#pragma unroll
    for (int j = 0; j < 8; j++) {
        int idx = t * 8 + j;
        v[j] = (idx < nbk) ? btot[idx] : 0;
        s += v[j];
    }
    ts[t] = s;
    __syncthreads();
    for (int off = 1; off < 256; off <<= 1) {
        int x = (t >= off) ? ts[t - off] : 0;
        __syncthreads();
        ts[t] += x;
        __syncthreads();
    }
    int run = ts[t] - s;
#pragma unroll
    for (int j = 0; j < 8; j++) {
        int idx = t * 8 + j;
        if (idx < nbk) { bbase[idx] = run; bucket_start[idx] = run; }
        run += v[j];
    }
    if (t == 255) { bucket_start[nbk] = n_edges; startv[n_nodes] = n_edges; }
}

__global__ __launch_bounds__(256) void col_off2_k(
    int* __restrict__ blockhist, const int* __restrict__ chunksum,
    const int* __restrict__ bbase, int nbk, int nblk, int nchk)
{
    int b = blockIdx.x * 256 + threadIdx.x;
    int c = blockIdx.y;
    if (b >= nbk) return;
    int k0 = c * CHK;
    int k1 = min(k0 + CHK, nblk);
    int run = bbase[b] + chunksum[(size_t)b * nchk + c];
    for (int k = k0; k < k1; k++) {
        size_t idx = (size_t)k * nbk + b;
        int v = blockhist[idx];
        blockhist[idx] = run;
        run += v;
    }
}

__global__ __launch_bounds__(256) void bin_scatter_k(
    const int* __restrict__ src, const int* __restrict__ dst,
    const int* __restrict__ blockhist, int* __restrict__ packedv,
    int n_edges, int nbk)
{
    extern __shared__ int cur[];
    const int* row = blockhist + (size_t)blockIdx.x * nbk;
    for (int i = threadIdx.x; i < nbk; i += 256) cur[i] = row[i];
    __syncthreads();
    int base = blockIdx.x * EPB;
    for (int i = threadIdx.x; i < EPB; i += 256) {
        int e = base + i;
        if (e < n_edges) {
            int d = dst[e];
            int pos = atomicAdd(&cur[d >> BSH], 1);
            packedv[pos] = ((d & 63) << 17) | src[e];
        }
    }
}

__global__ __launch_bounds__(256) void csr_k(
    const int* __restrict__ packedv, const int* __restrict__ bucket_start,
    int* __restrict__ nbr, int* __restrict__ startv, int n_nodes)
{
    __shared__ int hist[64];
    __shared__ int excl[64];
    __shared__ int cur[64];
    int b = blockIdx.x;
    int base = bucket_start[b];
    int end  = bucket_start[b + 1];
    if (threadIdx.x < 64) hist[threadIdx.x] = 0;
    __syncthreads();
    for (int i = base + threadIdx.x; i < end; i += 256)
        atomicAdd(&hist[packedv[i] >> 17], 1);
    __syncthreads();
    if (threadIdx.x == 0) {
        int r = 0;
        for (int k = 0; k < 64; k++) { excl[k] = r; r += hist[k]; }
    }
    __syncthreads();
    if (threadIdx.x < 64) {
        cur[threadIdx.x] = excl[threadIdx.x];
        int node = (b << 6) + threadIdx.x;
        if (node < n_nodes) startv[node] = base + excl[threadIdx.x];
    }
    __syncthreads();
    for (int i = base + threadIdx.x; i < end; i += 256) {
        int p = packedv[i];
        int pos = base + atomicAdd(&cur[p >> 17], 1);
        nbr[pos] = p & 0x1FFFF;
    }
}

// ---- shared gather core: returns hv[10] for (n,q); quad-reduced across the 4 lanes ----
__device__ __forceinline__ void gather_core(
    const float* __restrict__ A, const unsigned int* __restrict__ Bt,
    const f32x2 (&w1p)[10][5], const int* __restrict__ startv,
    const int* __restrict__ nbr, int n, int q, float (&hv)[10])
{
    const float4* ar = reinterpret_cast<const float4*>(A + (size_t)n * RS);
    float4 a0 = ar[0], a1 = ar[1], a2 = ar[2];
    f32x2 av2[5] = { {a0.x,a0.y}, {a0.z,a0.w}, {a1.x,a1.y}, {a1.z,a1.w}, {a2.x,a2.y} };

    f32x2 acc2[5];
#pragma unroll
    for (int h2 = 0; h2 < 5; h2++) acc2[h2] = (f32x2){0.f, 0.f};

    int beg = startv[n];
    int end = startv[n + 1];
    for (int i = beg + q; i < end; i += 4) {
        int s = nbr[i];
        uint4 d = *reinterpret_cast<const uint4*>(Bt + (size_t)s * BRS);
        unsigned int f0 = d.x & 0xFFFu;
        unsigned int f1 = (d.x >> 12) & 0xFFFu;
        unsigned int f2 = (d.x >> 24) | ((d.y & 0xFu) << 8);
        unsigned int f3 = (d.y >> 4) & 0xFFFu;
        unsigned int f4 = (d.y >> 16) & 0xFFFu;
        unsigned int f5 = ((d.y >> 28) & 0xFu) | ((d.z & 0xFFu) << 4);
        unsigned int f6 = (d.z >> 8) & 0xFFFu;
        unsigned int f7 = d.z >> 20;
        unsigned int f8 = d.w & 0xFFFu;
        unsigned int f9 = (d.w >> 12) & 0xFFFu;

        f32x2 pre[5];
        pre[0] = av2[0] + (f32x2){ fp12f(f0), fp12f(f1) };
        pre[1] = av2[1] + (f32x2){ fp12f(f2), fp12f(f3) };
        pre[2] = av2[2] + (f32x2){ fp12f(f4), fp12f(f5) };
        pre[3] = av2[3] + (f32x2){ fp12f(f6), fp12f(f7) };
        pre[4] = av2[4] + (f32x2){ fp12f(f8), fp12f(f9) };
#pragma unroll
        for (int k = 0; k < 5; k++) pre[k] = pk_max0(pre[k]);

        f32x2 z[5];
#pragma unroll
        for (int h2 = 0; h2 < 5; h2++) z[h2] = (f32x2){0.f, 0.f};
#pragma unroll
        for (int j2 = 0; j2 < 5; j2++) {
            f32x2 pa = (f32x2){ pre[j2].x, pre[j2].x };
            f32x2 pb = (f32x2){ pre[j2].y, pre[j2].y };
#pragma unroll
            for (int h2 = 0; h2 < 5; h2++) {
                z[h2] = pk_fma(pa, w1p[2 * j2][h2], z[h2]);
                z[h2] = pk_fma(pb, w1p[2 * j2 + 1][h2], z[h2]);
            }
        }
#pragma unroll
        for (int h2 = 0; h2 < 5; h2++) acc2[h2] += pk_max0(z[h2]);
    }

#pragma unroll
    for (int h2 = 0; h2 < 5; h2++) {
        acc2[h2].x += __shfl_xor(acc2[h2].x, 1);
        acc2[h2].y += __shfl_xor(acc2[h2].y, 1);
    }
#pragma unroll
    for (int h2 = 0; h2 < 5; h2++) {
        acc2[h2].x += __shfl_xor(acc2[h2].x, 2);
        acc2[h2].y += __shfl_xor(acc2[h2].y, 2);
    }
#pragma unroll
    for (int h2 = 0; h2 < 5; h2++) {
        hv[2 * h2]     = acc2[h2].x * 0.1f;
        hv[2 * h2 + 1] = acc2[h2].y * 0.1f;
    }
}

// ---------- Middle gather layers: h -> next A (fp32) + next B (fp12), fused pre ----------
__global__ __launch_bounds__(256) void gather_mid_k(
    const float* __restrict__ A, const unsigned int* __restrict__ Bt,
    const float* __restrict__ W1, const float* __restrict__ W2n,
    const int* __restrict__ startv, const int* __restrict__ nbr,
    float* __restrict__ An, unsigned int* __restrict__ Bn, int n_nodes)
{
    __shared__ float w2s[200];
    for (int i = threadIdx.x; i < 200; i += 256) w2s[i] = W2n[i];
    __syncthreads();

    f32x2 w1p[10][5];
#pragma unroll
    for (int j = 0; j < 10; j++)
#pragma unroll
        for (int h2 = 0; h2 < 5; h2++)
            w1p[j][h2] = (f32x2){ W1[j * 10 + 2 * h2], W1[j * 10 + 2 * h2 + 1] };

    int t = blockIdx.x * 256 + threadIdx.x;
    int n = t >> 2;
    int q = t & 3;
    if (n >= n_nodes) return;

    float hv[10];
    gather_core(A, Bt, w1p, startv, nbr, n, q, hv);

    if (q == 0) {
        float a[8];
#pragma unroll
        for (int h = 0; h < 8; h++) {
            float zz = 0.f;
#pragma unroll
            for (int k = 0; k < 10; k++) zz = fmaf(hv[k], w2s[k * 10 + h], zz);
            a[h] = zz;
        }
        float4* Ar = reinterpret_cast<float4*>(An + (size_t)n * RS);
        Ar[0] = make_float4(a[0], a[1], a[2], a[3]);
        Ar[1] = make_float4(a[4], a[5], a[6], a[7]);
    } else if (q == 1) {
        float a8 = 0.f, a9 = 0.f;
#pragma unroll
        for (int k = 0; k < 10; k++) {
            a8 = fmaf(hv[k], w2s[k * 10 + 8], a8);
            a9 = fmaf(hv[k], w2s[k * 10 + 9], a9);
        }
        *reinterpret_cast<float2*>(An + (size_t)n * RS + 8) = make_float2(a8, a9);
    } else if (q == 2) {
        float bb[10];
#pragma unroll
        for (int h = 0; h < 10; h++) {
            float zz = 0.f;
#pragma unroll
            for (int k = 0; k < 10; k++) zz = fmaf(hv[k], w2s[100 + k * 10 + h], zz);
            bb[h] = zz;
        }
        *reinterpret_cast<uint4*>(Bn + (size_t)n * BRS) = pack10(bb);
    }
}

// ---------- Last gather layer FUSED with final MLP: out = relu(relu(h@Wf1)@Wf2) ----------
// Block = 64 nodes (4 threads/node for gather, then 64x64 tile GEMM).
__global__ __launch_bounds__(256) void gather_fin_k(
    const float* __restrict__ A, const unsigned int* __restrict__ Bt,
    const float* __restrict__ W1,
    const int* __restrict__ startv, const int* __restrict__ nbr,
    const float* __restrict__ Wf1,  // [10,64]
    const float* __restrict__ Wf2,  // [64,64]
    float* __restrict__ out,        // [NN,64]
    int n_nodes)
{
    __shared__ float wf1[640];
    __shared__ float wf2s[4096];
    __shared__ float tT[4096];
    __shared__ float hvs[640];      // [64 nodes][10], stride 10

    for (int i = threadIdx.x; i < 640; i += 256) wf1[i] = Wf1[i];
    for (int i = threadIdx.x; i < 4096; i += 256) wf2s[i] = Wf2[i];

    f32x2 w1p[10][5];
#pragma unroll
    for (int j = 0; j < 10; j++)
#pragma unroll
        for (int h2 = 0; h2 < 5; h2++)
            w1p[j][h2] = (f32x2){ W1[j * 10 + 2 * h2], W1[j * 10 + 2 * h2 + 1] };

    int t0 = blockIdx.x * 256 + threadIdx.x;
    int n = t0 >> 2;
    int q = t0 & 3;
    int r = threadIdx.x >> 2;       // node index within block (0..63)

    float hv[10];
#pragma unroll
    for (int k = 0; k < 10; k++) hv[k] = 0.f;
    if (n < n_nodes)
        gather_core(A, Bt, w1p, startv, nbr, n, q, hv);

    if (q == 0) {
#pragma unroll
        for (int k = 0; k < 5; k++) hvs[r * 10 + k] = hv[k];
    } else if (q == 1) {
#pragma unroll
        for (int k = 5; k < 10; k++) hvs[r * 10 + k] = hv[k];
    }
    __syncthreads();

    // Stage 1: tT[c][r] = relu(hv[r] @ Wf1[:,c])
    {
        int rr = threadIdx.x & 63;
        int gg = threadIdx.x >> 6;
        float h[10];
#pragma unroll
        for (int k = 0; k < 10; k++) h[k] = hvs[rr * 10 + k];
#pragma unroll
        for (int j = 0; j < 16; j++) {
            int c = gg * 16 + j;
            float v = 0.f;
#pragma unroll
            for (int k = 0; k < 10; k++) v = fmaf(h[k], wf1[k * 64 + c], v);
            tT[c * 64 + rr] = fmaxf(v, 0.f);
        }
    }
    __syncthreads();

    // Stage 2: 4x4 register tile over [64 nodes x 64 cols]
    int node0 = blockIdx.x * 64;
    int r0 = (threadIdx.x >> 4) * 4;
    int c0 = (threadIdx.x & 15) * 4;
    float acc[4][4];
#pragma unroll
    for (int i = 0; i < 4; i++)
#pragma unroll
        for (int j = 0; j < 4; j++) acc[i][j] = 0.f;

    for (int k = 0; k < 64; k++) {
        float4 a = *reinterpret_cast<const float4*>(&tT[k * 64 + r0]);
        float4 b = *reinterpret_cast<const float4*>(&wf2s[k * 64 + c0]);
        float av[4] = { a.x, a.y, a.z, a.w };
        float bv[4] = { b.x, b.y, b.z, b.w };
#pragma unroll
        for (int i = 0; i < 4; i++)
#pragma unroll
            for (int j = 0; j < 4; j++)
                acc[i][j] = fmaf(av[i], bv[j], acc[i][j]);
    }

#pragma unroll
    for (int i = 0; i < 4; i++) {
        int node = node0 + r0 + i;
        if (node < n_nodes) {
            float4 o = make_float4(fmaxf(acc[i][0], 0.f), fmaxf(acc[i][1], 0.f),
                                   fmaxf(acc[i][2], 0.f), fmaxf(acc[i][3], 0.f));
            *reinterpret_cast<float4*>(&out[(size_t)node * FEAT + c0]) = o;
        }
    }
}

extern "C" void kernel_launch(void* const* d_in, const int* in_sizes, int n_in,
                              void* d_out, int out_size, void* d_ws, size_t ws_size,
                              hipStream_t stream) {
    const float* X    = (const float*)d_in[0];
    const float* W2_0 = (const float*)d_in[1];
    const float* W1_0 = (const float*)d_in[2];
    const float* W2_1 = (const float*)d_in[3];
    const float* W1_1 = (const float*)d_in[4];
    const float* W2_2 = (const float*)d_in[5];
    const float* W1_2 = (const float*)d_in[6];
    const float* Wf1  = (const float*)d_in[7];
    const float* Wf2  = (const float*)d_in[8];
    const int* src = (const int*)d_in[9];
    const int* dst = (const int*)d_in[10];
    float* out = (float*)d_out;

    const int n_edges = in_sizes[9];
    const int n_nodes = in_sizes[0] / FEAT;

    const int nbk  = (n_nodes + 63) >> 6;          // ~1563 buckets (<=2048 for scan_k)
    const int nblk = (n_edges + EPB - 1) / EPB;    // ~1221 binning blocks
    const int nchk = (nblk + CHK - 1) / CHK;       // ~39 column-prefix chunks

    const size_t h_elems = (size_t)n_nodes * RS;
    const size_t b_elems = (size_t)n_nodes * BRS;
    // ws layout (4B elems): A0 | A1 | B0 | B1 | nbr | packed | blockhist | chunksum | btot | bbase | bstart | startv
    const size_t offA0  = 0;
    const size_t offA1  = offA0 + h_elems;
    const size_t offB0  = offA1 + h_elems;
    const size_t offB1  = offB0 + b_elems;
    const size_t offNbr = offB1 + b_elems;
    const size_t offPk  = offNbr + (size_t)n_edges;
    const size_t offBh  = offPk + (size_t)n_edges;
    const size_t offCs  = offBh + (size_t)nblk * nbk;
    const size_t offBt  = offCs + (size_t)nbk * nchk;
    const size_t offBb  = offBt + (size_t)nbk;
    const size_t offBs  = offBb + (size_t)nbk;
    const size_t offSt  = offBs + (size_t)nbk + 1;

    float* A0           = (float*)d_ws + offA0;
    float* A1           = (float*)d_ws + offA1;
    unsigned int* B0    = (unsigned int*)d_ws + offB0;
    unsigned int* B1    = (unsigned int*)d_ws + offB1;
    int* nbr            = (int*)d_ws + offNbr;
    int* packedv        = (int*)d_ws + offPk;
    int* blockhist      = (int*)d_ws + offBh;
    int* chunksum       = (int*)d_ws + offCs;
    int* btot           = (int*)d_ws + offBt;
    int* bbase          = (int*)d_ws + offBb;
    int* bstart         = (int*)d_ws + offBs;
    int* startv         = (int*)d_ws + offSt;

    const int nb = (n_nodes + 255) / 256;
    const int gb = (n_nodes * 4 + 255) / 256;   // == ceil(n_nodes/64)
    const int cb = (nbk + 255) / 256;
    const size_t lds_bins = (size_t)nbk * 4;

    // ---- CSR build (R11-proven: LDS-cursor two-level counting sort) ----
    bin_hist_k<<<nblk, 256, lds_bins, stream>>>(dst, blockhist, n_edges, nbk);
    colchunk_sum_k<<<dim3(cb, nchk), 256, 0, stream>>>(blockhist, chunksum, nbk, nblk, nchk);
    chunk_scan_k<<<cb, 256, 0, stream>>>(chunksum, btot, nbk, nchk);
    scan_k<<<1, 256, 0, stream>>>(btot, bbase, bstart, startv, nbk, n_nodes, n_edges);
    col_off2_k<<<dim3(cb, nchk), 256, 0, stream>>>(blockhist, chunksum, bbase, nbk, nblk, nchk);
    bin_scatter_k<<<nblk, 256, lds_bins, stream>>>(src, dst, blockhist, packedv, n_edges, nbk);
    csr_k<<<nbk, 256, 0, stream>>>(packedv, bstart, nbr, startv, n_nodes);

    // ---- Layer 0 precompute + 2 mid gathers + fused last gather/final ----
    pre_l0<<<nb, 256, 0, stream>>>(X, W2_0, A0, B0, n_nodes);
    gather_mid_k<<<gb, 256, 0, stream>>>(A0, B0, W1_0, W2_1, startv, nbr, A1, B1, n_nodes);
    gather_mid_k<<<gb, 256, 0, stream>>>(A1, B1, W1_1, W2_2, startv, nbr, A0, B0, n_nodes);
    gather_fin_k<<<gb, 256, 0, stream>>>(A0, B0, W1_2, startv, nbr, Wf1, Wf2, out, n_nodes);
}